// Round 6
// baseline (181.829 us; speedup 1.0000x reference)
//
#include <hip/hip_runtime.h>
#include <math.h>

#define BATCH   4
#define S_LEN   2048
#define DMODEL  512
#define NHEADS  8
#define DHEAD   64
#define M_TOT   8192
#define ATT_SCALE 0.04419417382415922f   // 1/sqrt(512)
#define QSCALE (ATT_SCALE * 1.44269504088896f)  // fold log2(e): exp(s*SCALE)=exp2(qk) with Q pre-scaled

using short8  = __attribute__((ext_vector_type(8))) short;
using floatx4 = __attribute__((ext_vector_type(4))) float;

// fp32 -> bf16 RNE
__device__ __forceinline__ ushort f2bf(float f) {
    union { float f; unsigned u; } x; x.f = f;
    unsigned u = x.u + 0x7FFFu + ((x.u >> 16) & 1u);
    return (ushort)(u >> 16);
}
__device__ __forceinline__ unsigned pk2(float a, float b) {
    return (unsigned)f2bf(a) | ((unsigned)f2bf(b) << 16);
}
// fp32x2 -> packed bf16x2, round-half-up — hot-loop use
__device__ __forceinline__ unsigned pkr2(float a, float b) {
    unsigned ua = __float_as_uint(a) + 0x8000u;
    unsigned ub = __float_as_uint(b) + 0x8000u;
    return __builtin_amdgcn_perm(ub, ua, 0x07060302u);
}

// ---------------------------------------------------------------------------
// Preprocess (merged): blocks [0,4096) convert x fp32->bf16; blocks
// [4096,4352) transpose the four W's into WT[p][n][k] bf16.
// ---------------------------------------------------------------------------
__global__ __launch_bounds__(256) void prep(
    const float* __restrict__ x,
    const float* __restrict__ Wq, const float* __restrict__ Wk,
    const float* __restrict__ Wv, const float* __restrict__ Wo,
    ushort* __restrict__ xb, ushort* __restrict__ WT)
{
    const int bid = blockIdx.x;
    if (bid < 4096) {
        const int i = (bid * 256 + threadIdx.x) * 4;
        float4 f = *(const float4*)(x + i);
        uint2 o; o.x = pk2(f.x, f.y); o.y = pk2(f.z, f.w);
        *(uint2*)(xb + i) = o;
    } else {
        const int rb = bid - 4096;           // 256 blocks
        const int p  = rb >> 6;
        const int rem = rb & 63;
        const int n  = (rem >> 5) * 256 + threadIdx.x;
        const int k0 = (rem & 31) * 16;
        const float* W = (p == 0) ? Wq : (p == 1) ? Wk : (p == 2) ? Wv : Wo;
        unsigned u[8];
        #pragma unroll
        for (int j = 0; j < 8; ++j) {
            float a = W[(k0 + 2 * j)     * DMODEL + n];
            float b = W[(k0 + 2 * j + 1) * DMODEL + n];
            u[j] = pk2(a, b);
        }
        ushort* dst = WT + ((size_t)p * DMODEL + n) * DMODEL + k0;
        *(uint4*)dst       = *(uint4*)&u[0];
        *(uint4*)(dst + 8) = *(uint4*)&u[4];
    }
}

// ---------------------------------------------------------------------------
// Kernel 1: fused QKV projection, 128x128 tile, BK=32.
// Q outputs pre-scaled by QSCALE (softmax exp2 fold).  V routed through an
// LDS transpose -> coalesced [B,H,Dh,S] b128 stores.
// ---------------------------------------------------------------------------
__global__ __launch_bounds__(256, 4) void qkv_gemm(
    const ushort* __restrict__ xb, const ushort* __restrict__ WT,
    const float* __restrict__ bq, const float* __restrict__ bk, const float* __restrict__ bv,
    ushort* __restrict__ q, ushort* __restrict__ k, ushort* __restrict__ vT)
{
    __shared__ ushort SMEM[128 * 136];
    ushort (*A)[40] = (ushort(*)[40])SMEM;
    ushort (*B)[40] = (ushort(*)[40])(SMEM + 128 * 40);
    ushort (*CT)[136] = (ushort(*)[136])SMEM;

    const int tid = threadIdx.x;
    const int wv  = tid >> 6, lane = tid & 63, l16 = lane & 15, quad = lane >> 4;
    const int m0  = blockIdx.x * 128;
    const int ng0 = blockIdx.y * 128;
    const int p   = ng0 >> 9;
    const int n0  = ng0 & 511;
    const ushort* Wp  = WT + (size_t)p * DMODEL * DMODEL + (size_t)n0 * DMODEL;
    const float* bias = (p == 0) ? bq : (p == 1) ? bk : bv;
    const float scl   = (p == 0) ? QSCALE : 1.0f;

    const int wm = (wv & 1) * 64, wn = (wv >> 1) * 64;
    floatx4 acc[4][4] = {};
    const int ar = tid >> 1, ac = (tid & 1) * 16;

    for (int k0 = 0; k0 < DMODEL; k0 += 32) {
        uint4 a0 = *(const uint4*)(xb + (size_t)(m0 + ar) * DMODEL + k0 + ac);
        uint4 a1 = *(const uint4*)(xb + (size_t)(m0 + ar) * DMODEL + k0 + ac + 8);
        uint4 b0 = *(const uint4*)(Wp + (size_t)ar * DMODEL + k0 + ac);
        uint4 b1 = *(const uint4*)(Wp + (size_t)ar * DMODEL + k0 + ac + 8);
        *(uint4*)&A[ar][ac] = a0; *(uint4*)&A[ar][ac + 8] = a1;
        *(uint4*)&B[ar][ac] = b0; *(uint4*)&B[ar][ac + 8] = b1;
        __syncthreads();

        short8 af[4], bf[4];
        #pragma unroll
        for (int i = 0; i < 4; ++i) af[i] = *(const short8*)&A[wm + i * 16 + l16][quad * 8];
        #pragma unroll
        for (int c = 0; c < 4; ++c) bf[c] = *(const short8*)&B[wn + c * 16 + l16][quad * 8];
        #pragma unroll
        for (int i = 0; i < 4; ++i)
            #pragma unroll
            for (int c = 0; c < 4; ++c)
                acc[i][c] = __builtin_amdgcn_mfma_f32_16x16x32_bf16(af[i], bf[c], acc[i][c], 0, 0, 0);
        __syncthreads();
    }

    if (p < 2) {
        #pragma unroll
        for (int c = 0; c < 4; ++c) {
            const int n = n0 + wn + c * 16 + l16;
            const float bb = bias[n];
            const int h = n >> 6, dh = n & 63;
            #pragma unroll
            for (int i = 0; i < 4; ++i)
                #pragma unroll
                for (int r = 0; r < 4; ++r) {
                    const int m = m0 + wm + i * 16 + quad * 4 + r;
                    const int b = m >> 11, s = m & 2047;
                    const ushort val = f2bf((acc[i][c][r] + bb) * scl);
                    if (p == 0) q[((size_t)(b * NHEADS + h) * S_LEN + s) * DHEAD + dh] = val;
                    else        k[((size_t)(b * NHEADS + h) * S_LEN + s) * DHEAD + dh] = val;
                }
        }
    } else {
        #pragma unroll
        for (int c = 0; c < 4; ++c) {
            const int n = wn + c * 16 + l16;
            const float bb = bias[n0 + n];
            #pragma unroll
            for (int i = 0; i < 4; ++i) {
                uint2 o;
                o.x = pk2(acc[i][c][0] + bb, acc[i][c][1] + bb);
                o.y = pk2(acc[i][c][2] + bb, acc[i][c][3] + bb);
                *(uint2*)&CT[n][wm + i * 16 + quad * 4] = o;
            }
        }
        __syncthreads();
        const int n  = tid >> 1, mh = (tid & 1) * 64;
        const int gn = n0 + n;
        const int h  = gn >> 6, dh = gn & 63;
        const int b  = m0 >> 11, sb = (m0 & 2047) + mh;
        ushort* dst = vT + ((size_t)(b * NHEADS + h) * DHEAD + dh) * S_LEN + sb;
        #pragma unroll
        for (int j = 0; j < 8; ++j)
            *(uint4*)(dst + j * 8) = *(const uint4*)&CT[n][mh + j * 8];
    }
}

// ---------------------------------------------------------------------------
// Kernel 2: flash attention, S^T = K·Q^T, SPLIT-S over blockIdx.z.
// Partials are purely additive (no running max).  direct==1: single chunk,
// normalize and write bf16 att inline (round-5 path).
// ---------------------------------------------------------------------------
__global__ __launch_bounds__(256, 4) void attn(
    const ushort* __restrict__ Q, const ushort* __restrict__ K,
    const ushort* __restrict__ vT, ushort* __restrict__ att,
    float* __restrict__ Opart, float* __restrict__ Lpart,
    const int KT, const int direct)
{
    __shared__ ushort Klds[64][72];
    __shared__ ushort Vt[64][72];
    __shared__ ushort Plds[128][72];

    const int tid = threadIdx.x;
    const int wv  = tid >> 6, lane = tid & 63, l16 = lane & 15, quad = lane >> 4;
    const int q0  = blockIdx.x * 128;
    const int bh  = blockIdx.y;
    const int ck  = blockIdx.z;
    const int kbase = ck * KT;
    const ushort* Qh = Q  + (size_t)bh * S_LEN * DHEAD;
    const ushort* Kh = K  + (size_t)bh * S_LEN * DHEAD;
    const ushort* Vh = vT + (size_t)bh * DHEAD * S_LEN;

    short8 qf[2][2];
    #pragma unroll
    for (int ni = 0; ni < 2; ++ni) {
        const ushort* qrow = Qh + (size_t)(q0 + wv * 32 + ni * 16 + l16) * DHEAD;
        qf[0][ni] = *(const short8*)(qrow + quad * 8);
        qf[1][ni] = *(const short8*)(qrow + 32 + quad * 8);
    }

    floatx4 oacc[4][2] = {};
    float lsum[2] = {0.f, 0.f};

    const int srow = tid >> 2, sc0 = (tid & 3) * 16;
    uint4 ka, kb, va, vb;
    {
        const ushort* Ks = Kh + (size_t)(kbase * 64 + srow) * DHEAD + sc0;
        const ushort* Vs = Vh + (size_t)srow * S_LEN + kbase * 64 + sc0;
        ka = *(const uint4*)Ks; kb = *(const uint4*)(Ks + 8);
        va = *(const uint4*)Vs; vb = *(const uint4*)(Vs + 8);
    }

    for (int kt = 0; kt < KT; ++kt) {
        *(uint4*)&Klds[srow][sc0] = ka; *(uint4*)&Klds[srow][sc0 + 8] = kb;
        *(uint4*)&Vt[srow][sc0]   = va; *(uint4*)&Vt[srow][sc0 + 8]   = vb;
        __syncthreads();

        if (kt + 1 < KT) {
            const ushort* Ks = Kh + (size_t)((kbase + kt + 1) * 64 + srow) * DHEAD + sc0;
            const ushort* Vs = Vh + (size_t)srow * S_LEN + (kbase + kt + 1) * 64 + sc0;
            ka = *(const uint4*)Ks; kb = *(const uint4*)(Ks + 8);
            va = *(const uint4*)Vs; vb = *(const uint4*)(Vs + 8);
        }

        floatx4 sc[4][2] = {};
        #pragma unroll
        for (int s = 0; s < 2; ++s)
            #pragma unroll
            for (int mi = 0; mi < 4; ++mi) {
                short8 kf = *(const short8*)&Klds[mi * 16 + l16][s * 32 + quad * 8];
                #pragma unroll
                for (int ni = 0; ni < 2; ++ni)
                    sc[mi][ni] = __builtin_amdgcn_mfma_f32_16x16x32_bf16(kf, qf[s][ni], sc[mi][ni], 0, 0, 0);
            }

        // Q carries SCALE*log2e -> bare v_exp_f32
        #pragma unroll
        for (int mi = 0; mi < 4; ++mi)
            #pragma unroll
            for (int ni = 0; ni < 2; ++ni) {
                const float p0 = __builtin_amdgcn_exp2f(sc[mi][ni][0]);
                const float p1 = __builtin_amdgcn_exp2f(sc[mi][ni][1]);
                const float p2 = __builtin_amdgcn_exp2f(sc[mi][ni][2]);
                const float p3 = __builtin_amdgcn_exp2f(sc[mi][ni][3]);
                lsum[ni] += (p0 + p1) + (p2 + p3);
                uint2 o; o.x = pkr2(p0, p1); o.y = pkr2(p2, p3);
                *(uint2*)&Plds[wv * 32 + ni * 16 + l16][mi * 16 + quad * 4] = o;
            }

        #pragma unroll
        for (int s = 0; s < 2; ++s) {
            short8 pf[2];
            #pragma unroll
            for (int ni = 0; ni < 2; ++ni)
                pf[ni] = *(const short8*)&Plds[wv * 32 + ni * 16 + l16][s * 32 + quad * 8];
            #pragma unroll
            for (int mi = 0; mi < 4; ++mi) {
                short8 vf = *(const short8*)&Vt[mi * 16 + l16][s * 32 + quad * 8];
                #pragma unroll
                for (int ni = 0; ni < 2; ++ni)
                    oacc[mi][ni] = __builtin_amdgcn_mfma_f32_16x16x32_bf16(vf, pf[ni], oacc[mi][ni], 0, 0, 0);
            }
        }
        __syncthreads();
    }

    float tot[2];
    #pragma unroll
    for (int ni = 0; ni < 2; ++ni) {
        float t = lsum[ni];
        t += __shfl_xor(t, 16, 64);
        t += __shfl_xor(t, 32, 64);
        tot[ni] = t;
    }

    if (direct) {
        const int b = bh >> 3, h = bh & 7;
        #pragma unroll
        for (int ni = 0; ni < 2; ++ni) {
            const float inv = 1.f / tot[ni];
            const int qi = q0 + wv * 32 + ni * 16 + l16;
            ushort* dst = att + ((size_t)(b * S_LEN + qi)) * DMODEL + h * DHEAD;
            #pragma unroll
            for (int mi = 0; mi < 4; ++mi) {
                uint2 o;
                o.x = pk2(oacc[mi][ni][0] * inv, oacc[mi][ni][1] * inv);
                o.y = pk2(oacc[mi][ni][2] * inv, oacc[mi][ni][3] * inv);
                *(uint2*)(dst + mi * 16 + quad * 4) = o;
            }
        }
    } else {
        // partial rows: row index = (ck*32+bh)*2048 + qi
        #pragma unroll
        for (int ni = 0; ni < 2; ++ni) {
            const int qi = q0 + wv * 32 + ni * 16 + l16;
            const size_t row = (size_t)(ck * 32 + bh) * S_LEN + qi;
            if (quad == 0) Lpart[row] = tot[ni];
            #pragma unroll
            for (int mi = 0; mi < 4; ++mi) {
                float4 o = { oacc[mi][ni][0], oacc[mi][ni][1],
                             oacc[mi][ni][2], oacc[mi][ni][3] };
                *(float4*)&Opart[row * DHEAD + mi * 16 + quad * 4] = o;
            }
        }
    }
}

// ---------------------------------------------------------------------------
// Kernel 2b: combine split-S partials -> bf16 att (only when SPLIT==2).
// ---------------------------------------------------------------------------
__global__ __launch_bounds__(256) void combine(
    const float* __restrict__ Opart, const float* __restrict__ Lpart,
    ushort* __restrict__ att)
{
    const int idx = blockIdx.x * 256 + threadIdx.x;
    const int row = idx >> 3;            // bh*2048 + q
    const int dho = (idx & 7) * 8;
    const int bh = row >> 11, qq = row & 2047;
    const float* o0 = Opart + (size_t)row * DHEAD + dho;
    const float* o1 = Opart + (size_t)(65536 + row) * DHEAD + dho;
    float4 a0 = *(const float4*)o0,       a1 = *(const float4*)(o0 + 4);
    float4 b0 = *(const float4*)o1,       b1 = *(const float4*)(o1 + 4);
    const float inv = 1.f / (Lpart[row] + Lpart[65536 + row]);
    uint4 u;
    u.x = pk2((a0.x + b0.x) * inv, (a0.y + b0.y) * inv);
    u.y = pk2((a0.z + b0.z) * inv, (a0.w + b0.w) * inv);
    u.z = pk2((a1.x + b1.x) * inv, (a1.y + b1.y) * inv);
    u.w = pk2((a1.z + b1.z) * inv, (a1.w + b1.w) * inv);
    ushort* dst = att + ((size_t)((bh >> 3) * S_LEN + qq)) * DMODEL + (bh & 7) * DHEAD + dho;
    *(uint4*)dst = u;
}

// ---------------------------------------------------------------------------
// Kernel 3: output projection, 128x128; out fp32.
// ---------------------------------------------------------------------------
__global__ __launch_bounds__(256, 4) void out_gemm(
    const ushort* __restrict__ att, const ushort* __restrict__ WoT,
    const float* __restrict__ bo, float* __restrict__ out)
{
    __shared__ ushort A[128][40];
    __shared__ ushort B[128][40];

    const int tid = threadIdx.x;
    const int wv  = tid >> 6, lane = tid & 63, l16 = lane & 15, quad = lane >> 4;
    const int m0 = blockIdx.x * 128;
    const int n0 = blockIdx.y * 128;

    const int wm = (wv & 1) * 64, wn = (wv >> 1) * 64;
    floatx4 acc[4][4] = {};
    const int ar = tid >> 1, ac = (tid & 1) * 16;

    for (int k0 = 0; k0 < DMODEL; k0 += 32) {
        uint4 a0 = *(const uint4*)(att + (size_t)(m0 + ar) * DMODEL + k0 + ac);
        uint4 a1 = *(const uint4*)(att + (size_t)(m0 + ar) * DMODEL + k0 + ac + 8);
        uint4 b0 = *(const uint4*)(WoT + (size_t)(n0 + ar) * DMODEL + k0 + ac);
        uint4 b1 = *(const uint4*)(WoT + (size_t)(n0 + ar) * DMODEL + k0 + ac + 8);
        *(uint4*)&A[ar][ac] = a0; *(uint4*)&A[ar][ac + 8] = a1;
        *(uint4*)&B[ar][ac] = b0; *(uint4*)&B[ar][ac + 8] = b1;
        __syncthreads();

        short8 af[4], bf[4];
        #pragma unroll
        for (int i = 0; i < 4; ++i) af[i] = *(const short8*)&A[wm + i * 16 + l16][quad * 8];
        #pragma unroll
        for (int c = 0; c < 4; ++c) bf[c] = *(const short8*)&B[wn + c * 16 + l16][quad * 8];
        #pragma unroll
        for (int i = 0; i < 4; ++i)
            #pragma unroll
            for (int c = 0; c < 4; ++c)
                acc[i][c] = __builtin_amdgcn_mfma_f32_16x16x32_bf16(af[i], bf[c], acc[i][c], 0, 0, 0);
        __syncthreads();
    }

    #pragma unroll
    for (int c = 0; c < 4; ++c) {
        const int n = n0 + wn + c * 16 + l16;
        const float bb = bo[n];
        #pragma unroll
        for (int i = 0; i < 4; ++i)
            #pragma unroll
            for (int r = 0; r < 4; ++r) {
                const int m = m0 + wm + i * 16 + quad * 4 + r;
                out[(size_t)m * DMODEL + n] = acc[i][c][r] + bb;
            }
    }
}

// ---------------------------------------------------------------------------
extern "C" void kernel_launch(void* const* d_in, const int* in_sizes, int n_in,
                              void* d_out, int out_size, void* d_ws, size_t ws_size,
                              hipStream_t stream)
{
    const float* x  = (const float*)d_in[0];
    const float* Wq = (const float*)d_in[1];
    const float* bq = (const float*)d_in[2];
    const float* Wk = (const float*)d_in[3];
    const float* bk = (const float*)d_in[4];
    const float* Wv = (const float*)d_in[5];
    const float* bv = (const float*)d_in[6];
    const float* Wo = (const float*)d_in[7];
    const float* bo = (const float*)d_in[8];
    float* out = (float*)d_out;

    ushort* ws = (ushort*)d_ws;
    const size_t SZ = (size_t)M_TOT * DMODEL;
    ushort* xb  = ws;            // aliased by att after qkv consumes xb
    ushort* att = ws;
    ushort* WT  = ws + SZ;
    ushort* q   = WT + 4 * (size_t)DMODEL * DMODEL;
    ushort* k   = q + SZ;
    ushort* vT  = k + SZ;
    float*  Opart = (float*)(vT + SZ);                       // 16B-aligned offset
    float*  Lpart = Opart + 2 * (size_t)32 * S_LEN * DHEAD;  // after 2 chunks of O

    const size_t base_need  = (size_t)(vT + SZ - ws) * 2;                     // ~35.7 MB
    const size_t split_need = base_need + 2 * ((size_t)32 * S_LEN * DHEAD + 32 * S_LEN) * 4;
    const int SPLIT = (ws_size >= split_need) ? 2 : 1;

    prep<<<4096 + 256, 256, 0, stream>>>(x, Wq, Wk, Wv, Wo, xb, WT);

    qkv_gemm<<<dim3(M_TOT / 128, 3 * DMODEL / 128), 256, 0, stream>>>(
        xb, WT, bq, bk, bv, q, k, vT);

    attn<<<dim3(S_LEN / 128, BATCH * NHEADS, SPLIT), 256, 0, stream>>>(
        q, k, vT, att, Opart, Lpart, S_LEN / 64 / SPLIT, SPLIT == 1 ? 1 : 0);

    if (SPLIT == 2)
        combine<<<(32 * S_LEN * DHEAD / 8) / 256, 256, 0, stream>>>(Opart, Lpart, att);

    out_gemm<<<dim3(M_TOT / 128, DMODEL / 128), 256, 0, stream>>>(
        att, WT + 3 * (size_t)DMODEL * DMODEL, bo, out);
}